// Round 3
// baseline (644.284 us; speedup 1.0000x reference)
//
#include <hip/hip_runtime.h>
#include <hip/hip_bf16.h>
#include <cstdint>

#define D_IN 128
#define DK 32
#define NH 8
#define HD 256   // NH*DK
#define CW 768   // 3*HD : Q|K|V concatenated per node

typedef __attribute__((ext_vector_type(8))) short short8;
typedef __attribute__((ext_vector_type(4))) float f32x4;

__device__ inline float bf2f(unsigned short u) {
  union { unsigned int i; float f; } c;
  c.i = ((unsigned int)u) << 16;
  return c.f;
}
__device__ inline short f2bf(float f) {
  union { float f; unsigned int i; } c; c.f = f;
  unsigned int u = c.i;
  u = u + 0x7FFFu + ((u >> 16) & 1u);  // RNE
  return (short)(u >> 16);
}

// ---------- prep A: h[50000][128] f32 -> bf16 MFMA A-fragments ----------
// A[nt][kt][L][r] = h[nt*16 + (L&15)][kt*32 + (L>>4)*8 + r]
__global__ __launch_bounds__(256) void prep_h_kernel(
    const float* __restrict__ h, short8* __restrict__ Abuf, int nt_total) {
  __shared__ float hs[16][128];
  int nt = blockIdx.x;
  int t = threadIdx.x;
  {
    const float4* h4 = (const float4*)(h + (size_t)nt * 16 * 128);
    float4 v0 = h4[t * 2], v1 = h4[t * 2 + 1];
    int node = t >> 4, dim = (t & 15) * 8;
    hs[node][dim + 0] = v0.x; hs[node][dim + 1] = v0.y;
    hs[node][dim + 2] = v0.z; hs[node][dim + 3] = v0.w;
    hs[node][dim + 4] = v1.x; hs[node][dim + 5] = v1.y;
    hs[node][dim + 6] = v1.z; hs[node][dim + 7] = v1.w;
  }
  __syncthreads();
  int kt = t >> 6, L = t & 63;
  short8 o;
  int row = L & 15, k0 = kt * 32 + ((L >> 4) << 3);
  #pragma unroll
  for (int r = 0; r < 8; r++) o[r] = f2bf(hs[row][k0 + r]);
  Abuf[(size_t)(nt * 4 + kt) * 64 + L] = o;
}

// ---------- prep B: Wcat[128][768] -> bf16 MFMA B-fragments ----------
// B[ct][kt][L][r] = Wcat[kt*32 + (L>>4)*8 + r][ct*16 + (L&15)]
__global__ __launch_bounds__(256) void prep_w_kernel(
    const float* __restrict__ WQ, const float* __restrict__ WK,
    const float* __restrict__ WV, short8* __restrict__ Bbuf) {
  int ct = blockIdx.x;  // 0..47
  int t = threadIdx.x;
  int kt = t >> 6, L = t & 63;
  int col = ct * 16 + (L & 15);
  int type = col >> 8;
  const float* W = (type == 0) ? WQ : (type == 1) ? WK : WV;
  int head = (col & 255) >> 5;
  int kk = col & 31;
  int k0 = kt * 32 + ((L >> 4) << 3);
  short8 o;
  #pragma unroll
  for (int r = 0; r < 8; r++)
    o[r] = f2bf(W[head * (D_IN * DK) + (k0 + r) * DK + kk]);
  Bbuf[(size_t)(ct * 4 + kt) * 64 + L] = o;
}

// ---------- MFMA GEMM: QKV[n][768] = h @ Wcat ----------
__global__ __launch_bounds__(256) void gemm_qkv_kernel(
    const short8* __restrict__ Abuf, const short8* __restrict__ Bbuf,
    __hip_bfloat16* __restrict__ QKV, int nt_total) {
  int w = threadIdx.x >> 6;
  int L = threadIdx.x & 63;
  int nt = blockIdx.x * 4 + w;
  int cb = blockIdx.y;  // 0..3, 192 cols each
  if (nt >= nt_total) return;
  f32x4 acc[12];
  #pragma unroll
  for (int c = 0; c < 12; c++) acc[c] = (f32x4){0.f, 0.f, 0.f, 0.f};
  #pragma unroll
  for (int kt = 0; kt < 4; kt++) {
    short8 a = Abuf[(size_t)(nt * 4 + kt) * 64 + L];
    #pragma unroll
    for (int c = 0; c < 12; c++) {
      short8 b = Bbuf[(size_t)((cb * 12 + c) * 4 + kt) * 64 + L];
      acc[c] = __builtin_amdgcn_mfma_f32_16x16x32_bf16(a, b, acc[c], 0, 0, 0);
    }
  }
  int row0 = nt * 16 + ((L >> 4) << 2);
  int col0 = cb * 192 + (L & 15);
  #pragma unroll
  for (int c = 0; c < 12; c++) {
    #pragma unroll
    for (int r = 0; r < 4; r++) {
      QKV[(size_t)(row0 + r) * CW + col0 + c * 16] =
          __float2bfloat16(acc[c][r]);
    }
  }
}

// ---------------- CSR build ----------------
__global__ void hist_kernel(const int* __restrict__ row, int n_edge,
                            int* __restrict__ cnt) {
  int i = blockIdx.x * blockDim.x + threadIdx.x;
  if (i < n_edge) atomicAdd(&cnt[row[i]], 1);
}

__global__ __launch_bounds__(256) void scan1_kernel(
    const int* __restrict__ cnt, int n, int* __restrict__ exc,
    int* __restrict__ bsum) {
  __shared__ int s[256];
  int gid = blockIdx.x * 256 + threadIdx.x;
  int v = (gid < n) ? cnt[gid] : 0;
  s[threadIdx.x] = v;
  __syncthreads();
  #pragma unroll
  for (int off = 1; off < 256; off <<= 1) {
    int t = (threadIdx.x >= off) ? s[threadIdx.x - off] : 0;
    __syncthreads();
    s[threadIdx.x] += t;
    __syncthreads();
  }
  if (gid < n) exc[gid] = s[threadIdx.x] - v;
  if (threadIdx.x == 255) bsum[blockIdx.x] = s[255];
}

__global__ __launch_bounds__(256) void scan2_kernel(int* __restrict__ bsum,
                                                    int nb) {
  __shared__ int s[256];
  int v = (threadIdx.x < nb) ? bsum[threadIdx.x] : 0;
  s[threadIdx.x] = v;
  __syncthreads();
  #pragma unroll
  for (int off = 1; off < 256; off <<= 1) {
    int t = (threadIdx.x >= off) ? s[threadIdx.x - off] : 0;
    __syncthreads();
    s[threadIdx.x] += t;
    __syncthreads();
  }
  if (threadIdx.x < nb) bsum[threadIdx.x] = s[threadIdx.x] - v;
}

__global__ __launch_bounds__(256) void scan3_kernel(
    int* __restrict__ exc, const int* __restrict__ bsum, int n, int n_edge,
    int* __restrict__ cursor) {
  int gid = blockIdx.x * 256 + threadIdx.x;
  if (gid < n) {
    int o = exc[gid] + bsum[blockIdx.x];
    exc[gid] = o;
    cursor[gid] = o;
  }
  if (gid == 0) exc[n] = n_edge;
}

__global__ void scatter_kernel(const int* __restrict__ row,
                               const int* __restrict__ col, int n_edge,
                               int* __restrict__ cursor,
                               int* __restrict__ col_sorted) {
  int i = blockIdx.x * blockDim.x + threadIdx.x;
  if (i < n_edge) {
    int pos = atomicAdd(&cursor[row[i]], 1);
    col_sorted[pos] = col[i];
  }
}

// ---------------- Main attention: one block per destination node ----------------
#define CHUNK 64
__global__ __launch_bounds__(256) void attn_kernel(
    const __hip_bfloat16* __restrict__ QKV, const int* __restrict__ offsets,
    const int* __restrict__ col_sorted, float* __restrict__ out, int n_node) {
  int node = blockIdx.x;
  int tid = threadIdx.x;
  int head = tid >> 5;
  int lane = tid & 31;
  __shared__ int cols[CHUNK];
  __shared__ float ex[NH][CHUNK];
  int start = offsets[node], end = offsets[node + 1];

  // Q fragment for this head
  float qf[32];
  {
    const short8* qp = (const short8*)(QKV + (size_t)node * CW + head * 32);
    #pragma unroll
    for (int i = 0; i < 4; i++) {
      short8 qv = qp[i];
      #pragma unroll
      for (int r = 0; r < 8; r++) qf[i * 8 + r] = bf2f((unsigned short)qv[r]);
    }
  }

  float m = -INFINITY, denom = 0.f, acc = 0.f;
  for (int base = start; base < end; base += CHUNK) {
    int n = min(CHUNK, end - base);
    __syncthreads();
    if (tid < n) cols[tid] = col_sorted[base + tid];
    __syncthreads();
    float lmax = -INFINITY;
    for (int j = lane; j < n; j += 32) {
      const short8* kp =
          (const short8*)(QKV + (size_t)cols[j] * CW + HD + head * 32);
      float e = 0.f;
      #pragma unroll
      for (int i = 0; i < 4; i++) {
        short8 kv = kp[i];
        #pragma unroll
        for (int r = 0; r < 8; r++)
          e += qf[i * 8 + r] * bf2f((unsigned short)kv[r]);
      }
      e *= 0.17677669529663687f;  // 1/sqrt(32)
      ex[head][j] = e;
      lmax = fmaxf(lmax, e);
    }
    #pragma unroll
    for (int off = 16; off; off >>= 1)
      lmax = fmaxf(lmax, __shfl_xor(lmax, off, 32));
    float nm = fmaxf(m, lmax);
    float scale = __expf(m - nm);
    denom *= scale;
    acc *= scale;
    float lsum = 0.f;
    for (int j = lane; j < n; j += 32) {
      float e = __expf(ex[head][j] - nm);
      ex[head][j] = e;
      lsum += e;
    }
    #pragma unroll
    for (int off = 16; off; off >>= 1)
      lsum += __shfl_xor(lsum, off, 32);
    denom += lsum;
    m = nm;
    __syncthreads();
    for (int j = 0; j < n; j++) {
      float w = ex[head][j];
      float vv = bf2f(*(const unsigned short*)(QKV + (size_t)cols[j] * CW +
                                               2 * HD + head * 32 + lane));
      acc += w * vv;
    }
  }
  float res = (end > start) ? acc / denom : 0.f;
  out[(size_t)node * HD + tid] = res;
}

extern "C" void kernel_launch(void* const* d_in, const int* in_sizes, int n_in,
                              void* d_out, int out_size, void* d_ws,
                              size_t ws_size, hipStream_t stream) {
  const float* h = (const float*)d_in[0];
  const int* edge = (const int*)d_in[1];
  const float* WQ = (const float*)d_in[2];
  const float* WK = (const float*)d_in[3];
  const float* WV = (const float*)d_in[4];
  float* out = (float*)d_out;

  int n_node = in_sizes[0] / D_IN;
  int n_edge = in_sizes[1] / 2;
  const int* row = edge;
  const int* col = edge + n_edge;

  char* ws = (char*)d_ws;
  size_t off = 0;
  auto alloc = [&](size_t bytes) {
    void* p = ws + off;
    off += (bytes + 255) & ~(size_t)255;
    return p;
  };
  __hip_bfloat16* QKV = (__hip_bfloat16*)alloc((size_t)n_node * CW * 2);
  int nt_total = (n_node + 15) / 16;  // 3125
  short8* Abuf = (short8*)alloc((size_t)nt_total * 4 * 64 * 16);
  short8* Bbuf = (short8*)alloc((size_t)48 * 4 * 64 * 16);
  int* col_sorted = (int*)alloc((size_t)n_edge * 4);
  int* cnt = (int*)alloc((size_t)n_node * 4);
  int* offsets = (int*)alloc((size_t)(n_node + 1) * 4);
  int* cursor = (int*)alloc((size_t)n_node * 4);
  int* bsum = (int*)alloc(256 * 4);

  hipMemsetAsync(cnt, 0, (size_t)n_node * 4, stream);

  prep_h_kernel<<<nt_total, 256, 0, stream>>>(h, Abuf, nt_total);
  prep_w_kernel<<<48, 256, 0, stream>>>(WQ, WK, WV, Bbuf);
  gemm_qkv_kernel<<<dim3((nt_total + 3) / 4, 4), 256, 0, stream>>>(
      Abuf, Bbuf, QKV, nt_total);

  int nb_e = (n_edge + 255) / 256;
  hist_kernel<<<nb_e, 256, 0, stream>>>(row, n_edge, cnt);

  int nb = (n_node + 255) / 256;
  scan1_kernel<<<nb, 256, 0, stream>>>(cnt, n_node, offsets, bsum);
  scan2_kernel<<<1, 256, 0, stream>>>(bsum, nb);
  scan3_kernel<<<nb, 256, 0, stream>>>(offsets, bsum, n_node, n_edge, cursor);

  scatter_kernel<<<nb_e, 256, 0, stream>>>(row, col, n_edge, cursor, col_sorted);

  attn_kernel<<<n_node, 256, 0, stream>>>(QKV, offsets, col_sorted, out,
                                          n_node);
}

// Round 4
// 539.032 us; speedup vs baseline: 1.1953x; 1.1953x over previous
//
#include <hip/hip_runtime.h>
#include <hip/hip_bf16.h>
#include <cstdint>

#define D_IN 128
#define DK 32
#define NH 8
#define HD 256   // NH*DK

typedef __attribute__((ext_vector_type(8))) short short8;
typedef __attribute__((ext_vector_type(4))) float f32x4;

__device__ inline float bf2f(unsigned short u) {
  union { unsigned int i; float f; } c;
  c.i = ((unsigned int)u) << 16;
  return c.f;
}
__device__ inline short f2bf(float f) {
  union { float f; unsigned int i; } c; c.f = f;
  unsigned int u = c.i;
  u = u + 0x7FFFu + ((u >> 16) & 1u);  // RNE
  return (short)(u >> 16);
}

// ---------- prep A: h[50000][128] f32 -> bf16 MFMA A-fragments ----------
// A[nt][kt][L][r] = h[nt*16 + (L&15)][kt*32 + (L>>4)*8 + r]
__global__ __launch_bounds__(256) void prep_h_kernel(
    const float* __restrict__ h, short8* __restrict__ Abuf, int nt_total) {
  __shared__ float hs[16][128];
  int nt = blockIdx.x;
  int t = threadIdx.x;
  {
    const float4* h4 = (const float4*)(h + (size_t)nt * 16 * 128);
    float4 v0 = h4[t * 2], v1 = h4[t * 2 + 1];
    int node = t >> 4, dim = (t & 15) * 8;
    hs[node][dim + 0] = v0.x; hs[node][dim + 1] = v0.y;
    hs[node][dim + 2] = v0.z; hs[node][dim + 3] = v0.w;
    hs[node][dim + 4] = v1.x; hs[node][dim + 5] = v1.y;
    hs[node][dim + 6] = v1.z; hs[node][dim + 7] = v1.w;
  }
  __syncthreads();
  int kt = t >> 6, L = t & 63;
  short8 o;
  int row = L & 15, k0 = kt * 32 + ((L >> 4) << 3);
  #pragma unroll
  for (int r = 0; r < 8; r++) o[r] = f2bf(hs[row][k0 + r]);
  Abuf[(size_t)(nt * 4 + kt) * 64 + L] = o;
}

// ---------- prep B: Wcat[128][768] -> bf16 MFMA B-fragments ----------
// B[ct][kt][L][r] = Wcat[kt*32 + (L>>4)*8 + r][ct*16 + (L&15)]
__global__ __launch_bounds__(256) void prep_w_kernel(
    const float* __restrict__ WQ, const float* __restrict__ WK,
    const float* __restrict__ WV, short8* __restrict__ Bbuf) {
  int ct = blockIdx.x;  // 0..47
  int t = threadIdx.x;
  int kt = t >> 6, L = t & 63;
  int col = ct * 16 + (L & 15);
  int type = col >> 8;
  const float* W = (type == 0) ? WQ : (type == 1) ? WK : WV;
  int head = (col & 255) >> 5;
  int kk = col & 31;
  int k0 = kt * 32 + ((L >> 4) << 3);
  short8 o;
  #pragma unroll
  for (int r = 0; r < 8; r++)
    o[r] = f2bf(W[head * (D_IN * DK) + (k0 + r) * DK + kk]);
  Bbuf[(size_t)(ct * 4 + kt) * 64 + L] = o;
}

// ---------- MFMA GEMM: one block per 16-node tile, writes Q,K,V separate ----------
// wave w handles col-tiles ct = w*12 .. w*12+11 (cols w*192..w*192+191).
// Results staged in LDS [16][768] bf16, then 3x contiguous 8KB coalesced stores.
__global__ __launch_bounds__(256) void gemm_qkv_kernel(
    const short8* __restrict__ Abuf, const short8* __restrict__ Bbuf,
    __hip_bfloat16* __restrict__ Q, __hip_bfloat16* __restrict__ K,
    __hip_bfloat16* __restrict__ V, int nt_total) {
  __shared__ short lds[16][768];
  int w = threadIdx.x >> 6;
  int L = threadIdx.x & 63;
  int nt = blockIdx.x;
  f32x4 acc[12];
  #pragma unroll
  for (int c = 0; c < 12; c++) acc[c] = (f32x4){0.f, 0.f, 0.f, 0.f};
  #pragma unroll
  for (int kt = 0; kt < 4; kt++) {
    short8 a = Abuf[(size_t)(nt * 4 + kt) * 64 + L];
    #pragma unroll
    for (int c = 0; c < 12; c++) {
      short8 b = Bbuf[(size_t)((w * 12 + c) * 4 + kt) * 64 + L];
      acc[c] = __builtin_amdgcn_mfma_f32_16x16x32_bf16(a, b, acc[c], 0, 0, 0);
    }
  }
  int row0 = (L >> 4) << 2;
  int col0 = w * 192 + (L & 15);
  #pragma unroll
  for (int c = 0; c < 12; c++) {
    #pragma unroll
    for (int r = 0; r < 4; r++)
      lds[row0 + r][col0 + c * 16] = f2bf(acc[c][r]);
  }
  __syncthreads();
  // copy out: section s (0=Q,1=K,2=V) is rows 0..15 x cols s*256..s*256+255
  // = 16 rows x 512B, contiguous 8KB in the destination array.
  __hip_bfloat16* dst[3] = {Q, K, V};
  int t = threadIdx.x;
  #pragma unroll
  for (int s = 0; s < 3; s++) {
    char* base = (char*)(dst[s] + (size_t)nt * 16 * HD);
    #pragma unroll
    for (int j = 0; j < 2; j++) {
      int u = t + j * 256;        // 512 16B-units per section
      int row = u >> 5, uc = u & 31;
      float4 vdat = *(const float4*)((const char*)&lds[row][0] + s * 512 + uc * 16);
      *(float4*)(base + row * 512 + uc * 16) = vdat;
    }
  }
}

// ---------------- CSR build ----------------
__global__ void hist_kernel(const int* __restrict__ row, int n_edge,
                            int* __restrict__ cnt) {
  int i = blockIdx.x * blockDim.x + threadIdx.x;
  if (i < n_edge) atomicAdd(&cnt[row[i]], 1);
}

__global__ __launch_bounds__(256) void scan1_kernel(
    const int* __restrict__ cnt, int n, int* __restrict__ exc,
    int* __restrict__ bsum) {
  __shared__ int s[256];
  int gid = blockIdx.x * 256 + threadIdx.x;
  int v = (gid < n) ? cnt[gid] : 0;
  s[threadIdx.x] = v;
  __syncthreads();
  #pragma unroll
  for (int off = 1; off < 256; off <<= 1) {
    int t = (threadIdx.x >= off) ? s[threadIdx.x - off] : 0;
    __syncthreads();
    s[threadIdx.x] += t;
    __syncthreads();
  }
  if (gid < n) exc[gid] = s[threadIdx.x] - v;
  if (threadIdx.x == 255) bsum[blockIdx.x] = s[255];
}

__global__ __launch_bounds__(256) void scan2_kernel(int* __restrict__ bsum,
                                                    int nb) {
  __shared__ int s[256];
  int v = (threadIdx.x < nb) ? bsum[threadIdx.x] : 0;
  s[threadIdx.x] = v;
  __syncthreads();
  #pragma unroll
  for (int off = 1; off < 256; off <<= 1) {
    int t = (threadIdx.x >= off) ? s[threadIdx.x - off] : 0;
    __syncthreads();
    s[threadIdx.x] += t;
    __syncthreads();
  }
  if (threadIdx.x < nb) bsum[threadIdx.x] = s[threadIdx.x] - v;
}

__global__ __launch_bounds__(256) void scan3_kernel(
    int* __restrict__ exc, const int* __restrict__ bsum, int n, int n_edge,
    int* __restrict__ cursor) {
  int gid = blockIdx.x * 256 + threadIdx.x;
  if (gid < n) {
    int o = exc[gid] + bsum[blockIdx.x];
    exc[gid] = o;
    cursor[gid] = o;
  }
  if (gid == 0) exc[n] = n_edge;
}

__global__ void scatter_kernel(const int* __restrict__ row,
                               const int* __restrict__ col, int n_edge,
                               int* __restrict__ cursor,
                               int* __restrict__ col_sorted) {
  int i = blockIdx.x * blockDim.x + threadIdx.x;
  if (i < n_edge) {
    int pos = atomicAdd(&cursor[row[i]], 1);
    col_sorted[pos] = col[i];
  }
}

// ---------------- Main attention: one block per destination node ----------------
#define CHUNK 64
__global__ __launch_bounds__(256) void attn_kernel(
    const __hip_bfloat16* __restrict__ Q, const __hip_bfloat16* __restrict__ K,
    const __hip_bfloat16* __restrict__ V, const int* __restrict__ offsets,
    const int* __restrict__ col_sorted, float* __restrict__ out, int n_node) {
  int node = blockIdx.x;
  int tid = threadIdx.x;
  int head = tid >> 5;
  int lane = tid & 31;
  __shared__ int cols[CHUNK];
  __shared__ float ex[NH][CHUNK];
  int start = offsets[node], end = offsets[node + 1];

  // Q fragment for this head (broadcast read: 32 lanes read same 64B)
  float qf[32];
  {
    const short8* qp = (const short8*)(Q + (size_t)node * HD + head * 32);
    #pragma unroll
    for (int i = 0; i < 4; i++) {
      short8 qv = qp[i];
      #pragma unroll
      for (int r = 0; r < 8; r++) qf[i * 8 + r] = bf2f((unsigned short)qv[r]);
    }
  }

  float m = -INFINITY, denom = 0.f, acc = 0.f;
  for (int base = start; base < end; base += CHUNK) {
    int n = min(CHUNK, end - base);
    __syncthreads();
    if (tid < n) cols[tid] = col_sorted[base + tid];
    __syncthreads();
    float lmax = -INFINITY;
    for (int j = lane; j < n; j += 32) {
      const short8* kp = (const short8*)(K + (size_t)cols[j] * HD + head * 32);
      float e = 0.f;
      #pragma unroll
      for (int i = 0; i < 4; i++) {
        short8 kv = kp[i];
        #pragma unroll
        for (int r = 0; r < 8; r++)
          e += qf[i * 8 + r] * bf2f((unsigned short)kv[r]);
      }
      e *= 0.17677669529663687f;  // 1/sqrt(32)
      ex[head][j] = e;
      lmax = fmaxf(lmax, e);
    }
    #pragma unroll
    for (int off = 16; off; off >>= 1)
      lmax = fmaxf(lmax, __shfl_xor(lmax, off, 32));
    float nm = fmaxf(m, lmax);
    float scale = __expf(m - nm);
    denom *= scale;
    acc *= scale;
    float lsum = 0.f;
    for (int j = lane; j < n; j += 32) {
      float e = __expf(ex[head][j] - nm);
      ex[head][j] = e;
      lsum += e;
    }
    #pragma unroll
    for (int off = 16; off; off >>= 1)
      lsum += __shfl_xor(lsum, off, 32);
    denom += lsum;
    m = nm;
    __syncthreads();
    for (int j = 0; j < n; j++) {
      float w = ex[head][j];
      float vv = bf2f(*(const unsigned short*)(V + (size_t)cols[j] * HD +
                                               head * 32 + lane));
      acc += w * vv;
    }
  }
  float res = (end > start) ? acc / denom : 0.f;
  out[(size_t)node * HD + tid] = res;
}

extern "C" void kernel_launch(void* const* d_in, const int* in_sizes, int n_in,
                              void* d_out, int out_size, void* d_ws,
                              size_t ws_size, hipStream_t stream) {
  const float* h = (const float*)d_in[0];
  const int* edge = (const int*)d_in[1];
  const float* WQ = (const float*)d_in[2];
  const float* WK = (const float*)d_in[3];
  const float* WV = (const float*)d_in[4];
  float* out = (float*)d_out;

  int n_node = in_sizes[0] / D_IN;
  int n_edge = in_sizes[1] / 2;
  const int* row = edge;
  const int* col = edge + n_edge;

  char* ws = (char*)d_ws;
  size_t off = 0;
  auto alloc = [&](size_t bytes) {
    void* p = ws + off;
    off += (bytes + 255) & ~(size_t)255;
    return p;
  };
  int nt_total = (n_node + 15) / 16;  // 3125 (50000 = 3125*16 exactly)
  __hip_bfloat16* Q = (__hip_bfloat16*)alloc((size_t)nt_total * 16 * HD * 2);
  __hip_bfloat16* K = (__hip_bfloat16*)alloc((size_t)nt_total * 16 * HD * 2);
  __hip_bfloat16* V = (__hip_bfloat16*)alloc((size_t)nt_total * 16 * HD * 2);
  short8* Abuf = (short8*)alloc((size_t)nt_total * 4 * 64 * 16);
  short8* Bbuf = (short8*)alloc((size_t)48 * 4 * 64 * 16);
  int* col_sorted = (int*)alloc((size_t)n_edge * 4);
  int* cnt = (int*)alloc((size_t)n_node * 4);
  int* offsets = (int*)alloc((size_t)(n_node + 1) * 4);
  int* cursor = (int*)alloc((size_t)n_node * 4);
  int* bsum = (int*)alloc(256 * 4);

  hipMemsetAsync(cnt, 0, (size_t)n_node * 4, stream);

  prep_h_kernel<<<nt_total, 256, 0, stream>>>(h, Abuf, nt_total);
  prep_w_kernel<<<48, 256, 0, stream>>>(WQ, WK, WV, Bbuf);
  gemm_qkv_kernel<<<nt_total, 256, 0, stream>>>(Abuf, Bbuf, Q, K, V, nt_total);

  int nb_e = (n_edge + 255) / 256;
  hist_kernel<<<nb_e, 256, 0, stream>>>(row, n_edge, cnt);

  int nb = (n_node + 255) / 256;
  scan1_kernel<<<nb, 256, 0, stream>>>(cnt, n_node, offsets, bsum);
  scan2_kernel<<<1, 256, 0, stream>>>(bsum, nb);
  scan3_kernel<<<nb, 256, 0, stream>>>(offsets, bsum, n_node, n_edge, cursor);

  scatter_kernel<<<nb_e, 256, 0, stream>>>(row, col, n_edge, cursor, col_sorted);

  attn_kernel<<<n_node, 256, 0, stream>>>(Q, K, V, offsets, col_sorted, out,
                                          n_node);
}

// Round 5
// 427.092 us; speedup vs baseline: 1.5085x; 1.2621x over previous
//
#include <hip/hip_runtime.h>
#include <hip/hip_bf16.h>
#include <cstdint>

#define D_IN 128
#define DK 32
#define NH 8
#define HD 256   // NH*DK

typedef __attribute__((ext_vector_type(8))) short short8;
typedef __attribute__((ext_vector_type(4))) float f32x4;

__device__ inline float bf2f(unsigned short u) {
  union { unsigned int i; float f; } c;
  c.i = ((unsigned int)u) << 16;
  return c.f;
}
__device__ inline short f2bf(float f) {
  union { float f; unsigned int i; } c; c.f = f;
  unsigned int u = c.i;
  u = u + 0x7FFFu + ((u >> 16) & 1u);  // RNE
  return (short)(u >> 16);
}

// ---------- prep B: Wcat[128][768] -> bf16 MFMA B-fragments ----------
// B[ct][kt][L][r] = Wcat[kt*32 + (L>>4)*8 + r][ct*16 + (L&15)]
__global__ __launch_bounds__(256) void prep_w_kernel(
    const float* __restrict__ WQ, const float* __restrict__ WK,
    const float* __restrict__ WV, short8* __restrict__ Bbuf) {
  int ct = blockIdx.x;  // 0..47
  int t = threadIdx.x;
  int kt = t >> 6, L = t & 63;
  int col = ct * 16 + (L & 15);
  int type = col >> 8;
  const float* W = (type == 0) ? WQ : (type == 1) ? WK : WV;
  int head = (col & 255) >> 5;
  int kk = col & 31;
  int k0 = kt * 32 + ((L >> 4) << 3);
  short8 o;
  #pragma unroll
  for (int r = 0; r < 8; r++)
    o[r] = f2bf(W[head * (D_IN * DK) + (k0 + r) * DK + kk]);
  Bbuf[(size_t)(ct * 4 + kt) * 64 + L] = o;
}

// ---------- MFMA GEMM (h conversion fused): one block per 16-node tile ----------
__global__ __launch_bounds__(256) void gemm_qkv_kernel(
    const float* __restrict__ h, const short8* __restrict__ Bbuf,
    __hip_bfloat16* __restrict__ Q, __hip_bfloat16* __restrict__ K,
    __hip_bfloat16* __restrict__ V, int nt_total) {
  __shared__ float hs[16][132];   // +4 pad: conflict-free fragment reads
  __shared__ short lds[16][768];
  int nt = blockIdx.x;
  int t = threadIdx.x;
  {
    const float4* h4 = (const float4*)(h + (size_t)nt * 16 * 128);
    float4 v0 = h4[t * 2], v1 = h4[t * 2 + 1];
    int node = t >> 4, dim = (t & 15) * 8;
    hs[node][dim + 0] = v0.x; hs[node][dim + 1] = v0.y;
    hs[node][dim + 2] = v0.z; hs[node][dim + 3] = v0.w;
    hs[node][dim + 4] = v1.x; hs[node][dim + 5] = v1.y;
    hs[node][dim + 6] = v1.z; hs[node][dim + 7] = v1.w;
  }
  __syncthreads();
  int w = t >> 6;
  int L = t & 63;
  int arow = L & 15, k0base = ((L >> 4) << 3);
  short8 afrag[4];
  #pragma unroll
  for (int kt = 0; kt < 4; kt++) {
    #pragma unroll
    for (int r = 0; r < 8; r++)
      afrag[kt][r] = f2bf(hs[arow][kt * 32 + k0base + r]);
  }
  f32x4 acc[12];
  #pragma unroll
  for (int c = 0; c < 12; c++) acc[c] = (f32x4){0.f, 0.f, 0.f, 0.f};
  #pragma unroll
  for (int kt = 0; kt < 4; kt++) {
    #pragma unroll
    for (int c = 0; c < 12; c++) {
      short8 b = Bbuf[(size_t)((w * 12 + c) * 4 + kt) * 64 + L];
      acc[c] = __builtin_amdgcn_mfma_f32_16x16x32_bf16(afrag[kt], b, acc[c], 0, 0, 0);
    }
  }
  int row0 = (L >> 4) << 2;
  int col0 = w * 192 + (L & 15);
  #pragma unroll
  for (int c = 0; c < 12; c++) {
    #pragma unroll
    for (int r = 0; r < 4; r++)
      lds[row0 + r][col0 + c * 16] = f2bf(acc[c][r]);
  }
  __syncthreads();
  // copy out: section s (0=Q,1=K,2=V) = 16 rows x 512B contiguous per dst.
  __hip_bfloat16* dst[3] = {Q, K, V};
  #pragma unroll
  for (int s = 0; s < 3; s++) {
    char* base = (char*)(dst[s] + (size_t)nt * 16 * HD);
    #pragma unroll
    for (int j = 0; j < 2; j++) {
      int u = t + j * 256;        // 512 16B-units per section
      int row = u >> 5, uc = u & 31;
      float4 vdat = *(const float4*)((const char*)&lds[row][0] + s * 512 + uc * 16);
      *(float4*)(base + row * 512 + uc * 16) = vdat;
    }
  }
}

// ---------------- CSR build: rank (1 returning atomic/edge) + scan + free scatter ----------------
__global__ void rank_kernel(const int* __restrict__ row, int n_edge,
                            int* __restrict__ cnt, int* __restrict__ rank) {
  int i = blockIdx.x * blockDim.x + threadIdx.x;
  if (i < n_edge) rank[i] = atomicAdd(&cnt[row[i]], 1);
}

__global__ __launch_bounds__(256) void scan1_kernel(
    const int* __restrict__ cnt, int n, int* __restrict__ exc,
    int* __restrict__ bsum) {
  __shared__ int s[256];
  int gid = blockIdx.x * 256 + threadIdx.x;
  int v = (gid < n) ? cnt[gid] : 0;
  s[threadIdx.x] = v;
  __syncthreads();
  #pragma unroll
  for (int off = 1; off < 256; off <<= 1) {
    int t = (threadIdx.x >= off) ? s[threadIdx.x - off] : 0;
    __syncthreads();
    s[threadIdx.x] += t;
    __syncthreads();
  }
  if (gid < n) exc[gid] = s[threadIdx.x] - v;
  if (threadIdx.x == 255) bsum[blockIdx.x] = s[255];
}

__global__ __launch_bounds__(256) void scan2_kernel(int* __restrict__ bsum,
                                                    int nb) {
  __shared__ int s[256];
  int v = (threadIdx.x < nb) ? bsum[threadIdx.x] : 0;
  s[threadIdx.x] = v;
  __syncthreads();
  #pragma unroll
  for (int off = 1; off < 256; off <<= 1) {
    int t = (threadIdx.x >= off) ? s[threadIdx.x - off] : 0;
    __syncthreads();
    s[threadIdx.x] += t;
    __syncthreads();
  }
  if (threadIdx.x < nb) bsum[threadIdx.x] = s[threadIdx.x] - v;
}

__global__ __launch_bounds__(256) void scan3_kernel(
    int* __restrict__ exc, const int* __restrict__ bsum, int n, int n_edge) {
  int gid = blockIdx.x * 256 + threadIdx.x;
  if (gid < n) exc[gid] = exc[gid] + bsum[blockIdx.x];
  if (gid == 0) exc[n] = n_edge;
}

__global__ void scatter_kernel(const int* __restrict__ row,
                               const int* __restrict__ col,
                               const int* __restrict__ rank, int n_edge,
                               const int* __restrict__ offsets,
                               int* __restrict__ col_sorted) {
  int i = blockIdx.x * blockDim.x + threadIdx.x;
  if (i < n_edge) col_sorted[offsets[row[i]] + rank[i]] = col[i];
}

// ---------------- Main attention: one block per destination node ----------------
#define CHUNK 64
__global__ __launch_bounds__(256) void attn_kernel(
    const __hip_bfloat16* __restrict__ Q, const __hip_bfloat16* __restrict__ K,
    const __hip_bfloat16* __restrict__ V, const int* __restrict__ offsets,
    const int* __restrict__ col_sorted, float* __restrict__ out, int n_node) {
  int node = blockIdx.x;
  int tid = threadIdx.x;
  int head = tid >> 5;
  int lane = tid & 31;
  __shared__ int cols[CHUNK];
  __shared__ float ex[NH][CHUNK];
  int start = offsets[node], end = offsets[node + 1];

  // Q fragment for this head (broadcast read: 32 lanes read same 64B)
  float qf[32];
  {
    const short8* qp = (const short8*)(Q + (size_t)node * HD + head * 32);
    #pragma unroll
    for (int i = 0; i < 4; i++) {
      short8 qv = qp[i];
      #pragma unroll
      for (int r = 0; r < 8; r++) qf[i * 8 + r] = bf2f((unsigned short)qv[r]);
    }
  }

  float m = -INFINITY, denom = 0.f, acc = 0.f;
  for (int base = start; base < end; base += CHUNK) {
    int n = min(CHUNK, end - base);
    __syncthreads();
    if (tid < n) cols[tid] = col_sorted[base + tid];
    __syncthreads();
    float lmax = -INFINITY;
    for (int j = lane; j < n; j += 32) {
      const short8* kp = (const short8*)(K + (size_t)cols[j] * HD + head * 32);
      float e = 0.f;
      #pragma unroll
      for (int i = 0; i < 4; i++) {
        short8 kv = kp[i];
        #pragma unroll
        for (int r = 0; r < 8; r++)
          e += qf[i * 8 + r] * bf2f((unsigned short)kv[r]);
      }
      e *= 0.17677669529663687f;  // 1/sqrt(32)
      ex[head][j] = e;
      lmax = fmaxf(lmax, e);
    }
    #pragma unroll
    for (int off = 16; off; off >>= 1)
      lmax = fmaxf(lmax, __shfl_xor(lmax, off, 32));
    float nm = fmaxf(m, lmax);
    float scale = __expf(m - nm);
    denom *= scale;
    acc *= scale;
    float lsum = 0.f;
    for (int j = lane; j < n; j += 32) {
      float e = __expf(ex[head][j] - nm);
      ex[head][j] = e;
      lsum += e;
    }
    #pragma unroll
    for (int off = 16; off; off >>= 1)
      lsum += __shfl_xor(lsum, off, 32);
    denom += lsum;
    m = nm;
    __syncthreads();
    for (int j = 0; j < n; j++) {
      float w = ex[head][j];
      float vv = bf2f(*(const unsigned short*)(V + (size_t)cols[j] * HD +
                                               head * 32 + lane));
      acc += w * vv;
    }
  }
  float res = (end > start) ? acc / denom : 0.f;
  out[(size_t)node * HD + tid] = res;
}

extern "C" void kernel_launch(void* const* d_in, const int* in_sizes, int n_in,
                              void* d_out, int out_size, void* d_ws,
                              size_t ws_size, hipStream_t stream) {
  const float* h = (const float*)d_in[0];
  const int* edge = (const int*)d_in[1];
  const float* WQ = (const float*)d_in[2];
  const float* WK = (const float*)d_in[3];
  const float* WV = (const float*)d_in[4];
  float* out = (float*)d_out;

  int n_node = in_sizes[0] / D_IN;
  int n_edge = in_sizes[1] / 2;
  const int* row = edge;
  const int* col = edge + n_edge;

  char* ws = (char*)d_ws;
  size_t off = 0;
  auto alloc = [&](size_t bytes) {
    void* p = ws + off;
    off += (bytes + 255) & ~(size_t)255;
    return p;
  };
  int nt_total = (n_node + 15) / 16;  // 3125 (50000 = 3125*16 exactly)
  __hip_bfloat16* Q = (__hip_bfloat16*)alloc((size_t)nt_total * 16 * HD * 2);
  __hip_bfloat16* K = (__hip_bfloat16*)alloc((size_t)nt_total * 16 * HD * 2);
  __hip_bfloat16* V = (__hip_bfloat16*)alloc((size_t)nt_total * 16 * HD * 2);
  short8* Bbuf = (short8*)alloc((size_t)48 * 4 * 64 * 16);
  int* col_sorted = (int*)alloc((size_t)n_edge * 4);
  int* rank = (int*)alloc((size_t)n_edge * 4);
  int* cnt = (int*)alloc((size_t)n_node * 4);
  int* offsets = (int*)alloc((size_t)(n_node + 1) * 4);
  int* bsum = (int*)alloc(256 * 4);

  hipMemsetAsync(cnt, 0, (size_t)n_node * 4, stream);

  prep_w_kernel<<<48, 256, 0, stream>>>(WQ, WK, WV, Bbuf);
  gemm_qkv_kernel<<<nt_total, 256, 0, stream>>>(h, Bbuf, Q, K, V, nt_total);

  int nb_e = (n_edge + 255) / 256;
  rank_kernel<<<nb_e, 256, 0, stream>>>(row, n_edge, cnt, rank);

  int nb = (n_node + 255) / 256;
  scan1_kernel<<<nb, 256, 0, stream>>>(cnt, n_node, offsets, bsum);
  scan2_kernel<<<1, 256, 0, stream>>>(bsum, nb);
  scan3_kernel<<<nb, 256, 0, stream>>>(offsets, bsum, n_node, n_edge);

  scatter_kernel<<<nb_e, 256, 0, stream>>>(row, col, rank, n_edge, offsets,
                                           col_sorted);

  attn_kernel<<<n_node, 256, 0, stream>>>(Q, K, V, offsets, col_sorted, out,
                                          n_node);
}